// Round 1
// baseline (272.265 us; speedup 1.0000x reference)
//
#include <hip/hip_runtime.h>

// ---------------------------------------------------------------------------
// CrossAttention: B=8, T=S=1024, E=H=768, fp32 in/out, bf16 MFMA internally.
//
// Pipeline (all on `stream`):
//   1. convert_inputs : x, encoder_out fp32 -> bf16
//   2. transpose_w    : Wq,Wk,Wv,Wp fp32 [K][N] -> bf16 W^T [N][K]
//   3. proj_qkv       : q = x@Wq+bq, k = enc@Wk+bk (row-major bf16),
//                       v stored TRANSPOSED per batch [B][H][S] (for PV GEMM)
//   4. gemm_bt        : scores = q k^T * 1/sqrt(H)  (fp32, batched)
//   5. softmax_rows   : P = softmax(scores) -> bf16
//   6. gemm_bt        : ao = P @ V   (A=P, Bt=v_t, batched, bf16 out)
//   7. gemm_bt        : out = ao @ Wp + bp (fp32 out)
//
// GEMM core: m97 structure — 128x128 tile, BK=32, 4 waves (2x2 of 64x64),
// 16x16x32 bf16 MFMA, global_load_lds width=16 staging, B^T ([N][K]) input.
// ---------------------------------------------------------------------------

typedef __bf16 bf16x8 __attribute__((ext_vector_type(8)));
typedef float  f32x4  __attribute__((ext_vector_type(4)));

#define BM 128
#define BN 128
#define BK 32

__device__ __forceinline__ unsigned short f2bf(float f) {
    unsigned int u = __float_as_uint(f);
    u += 0x7fffu + ((u >> 16) & 1u);   // RNE; inputs are finite
    return (unsigned short)(u >> 16);
}

__device__ __forceinline__ void async_copy16(const void* g, void* s) {
    __builtin_amdgcn_global_load_lds(
        (const __attribute__((address_space(1))) void*)g,
        (__attribute__((address_space(3))) void*)s, 16, 0, 0);
}

// A: [M][K] bf16 row-major.  Bt: [N][K] bf16 row-major (i.e. B transposed).
// Exactly one of Cf (fp32) / Cb (bf16) is non-null.
// transC != 0 (only with Cb): store C^T per batch as [B=rr>>10][H=c][S=rr&1023]
__device__ __forceinline__ void gemm_core(
    const unsigned short* __restrict__ A,
    const unsigned short* __restrict__ Bt,
    int K,
    float* __restrict__ Cf, unsigned short* __restrict__ Cb,
    int ldc, int transC, const float* __restrict__ bias, float scale)
{
    __shared__ unsigned short As[BM * BK];
    __shared__ unsigned short Bs[BN * BK];

    const int tid  = threadIdx.x;
    const int lane = tid & 63;
    const int quad = lane >> 4;
    const int l16  = lane & 15;
    const int wave = tid >> 6;
    const int wm   = (wave >> 1) * 64;
    const int wn   = (wave & 1) * 64;

    const long row0 = (long)blockIdx.x * BM;
    const long col0 = (long)blockIdx.y * BN;

    const unsigned short* Ag = A + row0 * K;
    const unsigned short* Bg = Bt + col0 * K;

    f32x4 acc[4][4];
#pragma unroll
    for (int i = 0; i < 4; ++i)
#pragma unroll
        for (int j = 0; j < 4; ++j)
            acc[i][j] = f32x4{0.f, 0.f, 0.f, 0.f};

    for (int k0 = 0; k0 < K; k0 += BK) {
        // stage A-tile [128][32] and B-tile [128][32] (contiguous, lane-ordered
        // so global_load_lds's wave-uniform-base + lane*16 layout holds)
#pragma unroll
        for (int h = 0; h < 2; ++h) {
            const int c  = tid + h * 256;   // chunk id 0..511
            const int r  = c >> 2;          // row 0..127
            const int kc = (c & 3) * 8;     // k offset 0,8,16,24
            async_copy16(Ag + (long)r * K + k0 + kc, &As[c * 8]);
            async_copy16(Bg + (long)r * K + k0 + kc, &Bs[c * 8]);
        }
        __syncthreads();

        bf16x8 af[4], bfr[4];
#pragma unroll
        for (int i = 0; i < 4; ++i) {
            af[i]  = *(const bf16x8*)&As[(wm + i * 16 + l16) * BK + quad * 8];
            bfr[i] = *(const bf16x8*)&Bs[(wn + i * 16 + l16) * BK + quad * 8];
        }
#pragma unroll
        for (int i = 0; i < 4; ++i)
#pragma unroll
            for (int j = 0; j < 4; ++j)
                acc[i][j] = __builtin_amdgcn_mfma_f32_16x16x32_bf16(
                    af[i], bfr[j], acc[i][j], 0, 0, 0);
        __syncthreads();
    }

    // epilogue: C/D layout col=lane&15, row=quad*4+reg  [m89/m91 verified]
#pragma unroll
    for (int i = 0; i < 4; ++i) {
#pragma unroll
        for (int j = 0; j < 4; ++j) {
            const long r0 = row0 + wm + i * 16 + quad * 4;
            const long c  = col0 + wn + j * 16 + l16;
            const float bb = bias ? bias[c] : 0.0f;
#pragma unroll
            for (int r = 0; r < 4; ++r) {
                const float v = acc[i][j][r] * scale + bb;
                const long rr = r0 + r;
                if (Cb) {
                    if (transC) {
                        Cb[((rr >> 10) * 768 + c) * 1024 + (rr & 1023)] = f2bf(v);
                    } else {
                        Cb[rr * (long)ldc + c] = f2bf(v);
                    }
                } else {
                    Cf[rr * (long)ldc + c] = v;
                }
            }
        }
    }
}

// ---------------------------------------------------------------------------

__global__ __launch_bounds__(256) void convert_inputs(
    const float* __restrict__ x, const float* __restrict__ enc,
    unsigned short* __restrict__ xb, unsigned short* __restrict__ eb, int nper)
{
    const int i = blockIdx.x * 256 + threadIdx.x;   // float4 index
    const bool second = (i >= nper);
    const int idx = second ? i - nper : i;
    const float4 v = second ? ((const float4*)enc)[idx] : ((const float4*)x)[idx];
    ushort4 o;
    o.x = f2bf(v.x); o.y = f2bf(v.y); o.z = f2bf(v.z); o.w = f2bf(v.w);
    if (second) ((ushort4*)eb)[idx] = o;
    else        ((ushort4*)xb)[idx] = o;
}

__global__ __launch_bounds__(256) void transpose_w(
    const float* __restrict__ w0, const float* __restrict__ w1,
    const float* __restrict__ w2, const float* __restrict__ w3,
    unsigned short* __restrict__ o0, unsigned short* __restrict__ o1,
    unsigned short* __restrict__ o2, unsigned short* __restrict__ o3)
{
    const float* w; unsigned short* o;
    switch (blockIdx.z) {
        case 0:  w = w0; o = o0; break;
        case 1:  w = w1; o = o1; break;
        case 2:  w = w2; o = o2; break;
        default: w = w3; o = o3; break;
    }
    __shared__ float t[32][33];
    const int tx = threadIdx.x & 31;
    const int ty = threadIdx.x >> 5;          // 0..7
    const int k0 = blockIdx.x * 32;
    const int n0 = blockIdx.y * 32;
#pragma unroll
    for (int i = 0; i < 4; ++i)
        t[ty + i * 8][tx] = w[(long)(k0 + ty + i * 8) * 768 + n0 + tx];
    __syncthreads();
#pragma unroll
    for (int i = 0; i < 4; ++i)
        o[(long)(n0 + ty + i * 8) * 768 + k0 + tx] = f2bf(t[tx][ty + i * 8]);
}

__global__ __launch_bounds__(256) void proj_qkv(
    const unsigned short* __restrict__ xb, const unsigned short* __restrict__ eb,
    const unsigned short* __restrict__ wqt, const unsigned short* __restrict__ wkt,
    const unsigned short* __restrict__ wvt,
    const float* __restrict__ bq, const float* __restrict__ bk,
    const float* __restrict__ bv,
    unsigned short* __restrict__ q, unsigned short* __restrict__ k,
    unsigned short* __restrict__ vt)
{
    const unsigned short *A, *Bt; const float* bias; unsigned short* C;
    int trans = 0;
    switch (blockIdx.z) {
        case 0:  A = xb; Bt = wqt; bias = bq; C = q;  break;
        case 1:  A = eb; Bt = wkt; bias = bk; C = k;  break;
        default: A = eb; Bt = wvt; bias = bv; C = vt; trans = 1; break;
    }
    gemm_core(A, Bt, 768, nullptr, C, 768, trans, bias, 1.0f);
}

__global__ __launch_bounds__(256) void gemm_bt(
    const unsigned short* __restrict__ A, long sA,
    const unsigned short* __restrict__ Bt, long sB,
    float* __restrict__ Cf, unsigned short* __restrict__ Cb, long sC,
    int K, int ldc, const float* __restrict__ bias, float scale)
{
    const long z = blockIdx.z;
    gemm_core(A + z * sA, Bt + z * sB, K,
              Cf ? Cf + z * sC : nullptr,
              Cb ? Cb + z * sC : nullptr,
              ldc, 0, bias, scale);
}

__global__ __launch_bounds__(256) void softmax_rows(
    const float* __restrict__ S, unsigned short* __restrict__ P)
{
    const long row = blockIdx.x;                 // 8192 rows of 1024
    const float* s = S + row * 1024;
    unsigned short* p = P + row * 1024;
    const int tid  = threadIdx.x;
    const int lane = tid & 63;
    const int wave = tid >> 6;

    float4 v = ((const float4*)s)[tid];
    float m = fmaxf(fmaxf(v.x, v.y), fmaxf(v.z, v.w));
#pragma unroll
    for (int off = 32; off > 0; off >>= 1)
        m = fmaxf(m, __shfl_xor(m, off));
    __shared__ float redm[4], reds[4];
    if (lane == 0) redm[wave] = m;
    __syncthreads();
    m = fmaxf(fmaxf(redm[0], redm[1]), fmaxf(redm[2], redm[3]));

    const float e0 = __expf(v.x - m), e1 = __expf(v.y - m);
    const float e2 = __expf(v.z - m), e3 = __expf(v.w - m);
    float sum = e0 + e1 + e2 + e3;
#pragma unroll
    for (int off = 32; off > 0; off >>= 1)
        sum += __shfl_xor(sum, off);
    if (lane == 0) reds[wave] = sum;
    __syncthreads();
    const float inv = 1.0f / (reds[0] + reds[1] + reds[2] + reds[3]);

    ushort4 o;
    o.x = f2bf(e0 * inv); o.y = f2bf(e1 * inv);
    o.z = f2bf(e2 * inv); o.w = f2bf(e3 * inv);
    ((ushort4*)p)[tid] = o;
}

// ---------------------------------------------------------------------------

extern "C" void kernel_launch(void* const* d_in, const int* in_sizes, int n_in,
                              void* d_out, int out_size, void* d_ws, size_t ws_size,
                              hipStream_t stream) {
    const float* x   = (const float*)d_in[0];
    const float* enc = (const float*)d_in[1];
    const float* Wq  = (const float*)d_in[2];
    const float* bq  = (const float*)d_in[3];
    const float* Wk  = (const float*)d_in[4];
    const float* bk  = (const float*)d_in[5];
    const float* Wv  = (const float*)d_in[6];
    const float* bv  = (const float*)d_in[7];
    const float* Wp  = (const float*)d_in[8];
    const float* bp  = (const float*)d_in[9];
    float* out = (float*)d_out;

    // workspace layout (bytes); peak need ~101.2 MB
    char* ws = (char*)d_ws;
    unsigned short* xb  = (unsigned short*)(ws + 0);         // 12582912
    unsigned short* eb  = (unsigned short*)(ws + 12582912);  // 12582912
    unsigned short* q   = (unsigned short*)(ws + 25165824);  // 12582912
    unsigned short* k   = (unsigned short*)(ws + 37748736);  // 12582912
    unsigned short* vt  = (unsigned short*)(ws + 50331648);  // 12582912 [B][H][S]
    unsigned short* wqt = (unsigned short*)(ws + 62914560);  // 1179648
    unsigned short* wkt = (unsigned short*)(ws + 64094208);  // 1179648
    unsigned short* wvt = (unsigned short*)(ws + 65273856);  // 1179648
    unsigned short* wpt = (unsigned short*)(ws + 66453504);  // 1179648
    float*          sc  = (float*)(ws + 67633152);           // 33554432 fp32 scores
    unsigned short* p   = (unsigned short*)(ws + 0);         // 16777216, overlays xb/eb (dead)
    unsigned short* ao  = (unsigned short*)(ws + 67633152);  // 12582912, overlays sc (dead)

    const float scale = 0.03608439182435161f;  // 1/sqrt(768)

    // 1. fp32 -> bf16 for x and encoder_out (6291456 floats each, float4-wide)
    convert_inputs<<<12288, 256, 0, stream>>>(x, enc, xb, eb, 1572864);

    // 2. W^T bf16 for all four weights
    transpose_w<<<dim3(24, 24, 4), 256, 0, stream>>>(Wq, Wk, Wv, Wp, wqt, wkt, wvt, wpt);

    // 3. q/k/v projections (z: 0=q, 1=k, 2=v-transposed)
    proj_qkv<<<dim3(64, 6, 3), 256, 0, stream>>>(xb, eb, wqt, wkt, wvt, bq, bk, bv, q, k, vt);

    // 4. scores = q k^T * scale (fp32), batched over z=8
    gemm_bt<<<dim3(8, 8, 8), 256, 0, stream>>>(
        q, 786432L, k, 786432L, sc, (unsigned short*)nullptr, 1048576L,
        768, 1024, (const float*)nullptr, scale);

    // 5. softmax rows -> bf16 P
    softmax_rows<<<8192, 256, 0, stream>>>(sc, p);

    // 6. ao = P @ V  (Bt = v_t [H][S]), batched
    gemm_bt<<<dim3(8, 6, 8), 256, 0, stream>>>(
        p, 1048576L, vt, 786432L, (float*)nullptr, ao, 786432L,
        1024, 768, (const float*)nullptr, 1.0f);

    // 7. out = ao @ Wp + bp (fp32)
    gemm_bt<<<dim3(64, 6, 1), 256, 0, stream>>>(
        ao, 0L, wpt, 0L, out, (unsigned short*)nullptr, 0L,
        768, 768, bp, 1.0f);
}

// Round 2
// 264.460 us; speedup vs baseline: 1.0295x; 1.0295x over previous
//
#include <hip/hip_runtime.h>

// ---------------------------------------------------------------------------
// CrossAttention: B=8, T=S=1024, E=H=768, fp32 in/out, bf16 MFMA internally.
//
// Round 2: GEMM core upgraded —
//  * double-buffered LDS with prefetch (loads for k+1 issued before compute k)
//  * XOR-swizzled staging layout (source-address permute; kills the 8-way
//    ds_read_b128 bank conflicts; read-side ends at free 2-way)
//  * template BN (128 for projections, 64 for the grid-starved GEMMs)
// ---------------------------------------------------------------------------

typedef __bf16 bf16x8 __attribute__((ext_vector_type(8)));
typedef float  f32x4  __attribute__((ext_vector_type(4)));

#define BM 128
#define BK 32

__device__ __forceinline__ unsigned short f2bf(float f) {
    unsigned int u = __float_as_uint(f);
    u += 0x7fffu + ((u >> 16) & 1u);   // RNE; inputs are finite
    return (unsigned short)(u >> 16);
}

__device__ __forceinline__ void async_copy16(const void* g, void* s) {
    __builtin_amdgcn_global_load_lds(
        (const __attribute__((address_space(1))) void*)g,
        (__attribute__((address_space(3))) void*)s, 16, 0, 0);
}

// A: [M][K] bf16 row-major.  Bt: [N][K] bf16 row-major (i.e. B transposed).
// Exactly one of Cf (fp32) / Cb (bf16) is non-null.
// transC != 0 (only with Cb): store C^T per batch as [B=rr>>10][H=c][S=rr&1023]
template<int BNT>
__device__ __forceinline__ void gemm_core(
    const unsigned short* __restrict__ A,
    const unsigned short* __restrict__ Bt,
    int K,
    float* __restrict__ Cf, unsigned short* __restrict__ Cb,
    int ldc, int transC, const float* __restrict__ bias, float scale)
{
    constexpr int NW = BNT / 32;          // B-frags per wave (128->4, 64->2)
    __shared__ unsigned short As[2][BM * BK];
    __shared__ unsigned short Bs[2][BNT * BK];

    const int tid  = threadIdx.x;
    const int lane = tid & 63;
    const int quad = lane >> 4;
    const int l16  = lane & 15;
    const int wave = tid >> 6;
    const int wm   = (wave >> 1) * 64;
    const int wn   = (wave & 1) * (BNT / 2);

    const long row0 = (long)blockIdx.x * BM;
    const long col0 = (long)blockIdx.y * BNT;

    const unsigned short* Ag = A + row0 * K;
    const unsigned short* Bg = Bt + col0 * K;

    // stage tile at k0 into buffer `buf`; source column XOR-swizzled so the
    // read side (chunk q at slot q ^ ((r>>1)&3)) is bank-conflict-free.
    auto stage = [&](int buf, int k0) {
#pragma unroll
        for (int h = 0; h < 2; ++h) {
            const int c  = tid + h * 256;              // A chunk 0..511
            const int r  = c >> 2;
            const int jj = (c & 3) ^ ((c >> 3) & 3);   // swizzled k-chunk
            async_copy16(Ag + (long)r * K + k0 + jj * 8, &As[buf][c * 8]);
        }
        if (BNT == 128) {
#pragma unroll
            for (int h = 0; h < 2; ++h) {
                const int c  = tid + h * 256;
                const int r  = c >> 2;
                const int jj = (c & 3) ^ ((c >> 3) & 3);
                async_copy16(Bg + (long)r * K + k0 + jj * 8, &Bs[buf][c * 8]);
            }
        } else {
            const int c  = tid;                        // B chunk 0..255
            const int r  = c >> 2;
            const int jj = (c & 3) ^ ((c >> 3) & 3);
            async_copy16(Bg + (long)r * K + k0 + jj * 8, &Bs[buf][c * 8]);
        }
    };

    f32x4 acc[4][NW];
#pragma unroll
    for (int i = 0; i < 4; ++i)
#pragma unroll
        for (int j = 0; j < NW; ++j)
            acc[i][j] = f32x4{0.f, 0.f, 0.f, 0.f};

    const int sw = (quad ^ ((l16 >> 1) & 3)) * 8;      // swizzled read slot
    const int nk = K / BK;

    stage(0, 0);
    for (int t = 0; t < nk; ++t) {
        const int buf = t & 1;
        __syncthreads();                 // drains vmcnt(0): tile t is in LDS
        if (t + 1 < nk) stage(buf ^ 1, (t + 1) * BK);  // prefetch next tile

        bf16x8 af[4], bfr[NW];
#pragma unroll
        for (int i = 0; i < 4; ++i)
            af[i]  = *(const bf16x8*)&As[buf][(wm + i * 16 + l16) * BK + sw];
#pragma unroll
        for (int j = 0; j < NW; ++j)
            bfr[j] = *(const bf16x8*)&Bs[buf][(wn + j * 16 + l16) * BK + sw];
#pragma unroll
        for (int i = 0; i < 4; ++i)
#pragma unroll
            for (int j = 0; j < NW; ++j)
                acc[i][j] = __builtin_amdgcn_mfma_f32_16x16x32_bf16(
                    af[i], bfr[j], acc[i][j], 0, 0, 0);
    }

    // epilogue: C/D layout col=lane&15, row=quad*4+reg  [m89/m91 verified]
#pragma unroll
    for (int i = 0; i < 4; ++i) {
#pragma unroll
        for (int j = 0; j < NW; ++j) {
            const long r0 = row0 + wm + i * 16 + quad * 4;
            const long c  = col0 + wn + j * 16 + l16;
            const float bb = bias ? bias[c] : 0.0f;
#pragma unroll
            for (int r = 0; r < 4; ++r) {
                const float v = acc[i][j][r] * scale + bb;
                const long rr = r0 + r;
                if (Cb) {
                    if (transC) {
                        Cb[((rr >> 10) * 768 + c) * 1024 + (rr & 1023)] = f2bf(v);
                    } else {
                        Cb[rr * (long)ldc + c] = f2bf(v);
                    }
                } else {
                    Cf[rr * (long)ldc + c] = v;
                }
            }
        }
    }
}

// ---------------------------------------------------------------------------

__global__ __launch_bounds__(256) void convert_inputs(
    const float* __restrict__ x, const float* __restrict__ enc,
    unsigned short* __restrict__ xb, unsigned short* __restrict__ eb, int nper)
{
    const int i = blockIdx.x * 256 + threadIdx.x;   // float4 index
    const bool second = (i >= nper);
    const int idx = second ? i - nper : i;
    const float4 v = second ? ((const float4*)enc)[idx] : ((const float4*)x)[idx];
    ushort4 o;
    o.x = f2bf(v.x); o.y = f2bf(v.y); o.z = f2bf(v.z); o.w = f2bf(v.w);
    if (second) ((ushort4*)eb)[idx] = o;
    else        ((ushort4*)xb)[idx] = o;
}

__global__ __launch_bounds__(256) void transpose_w(
    const float* __restrict__ w0, const float* __restrict__ w1,
    const float* __restrict__ w2, const float* __restrict__ w3,
    unsigned short* __restrict__ o0, unsigned short* __restrict__ o1,
    unsigned short* __restrict__ o2, unsigned short* __restrict__ o3)
{
    const float* w; unsigned short* o;
    switch (blockIdx.z) {
        case 0:  w = w0; o = o0; break;
        case 1:  w = w1; o = o1; break;
        case 2:  w = w2; o = o2; break;
        default: w = w3; o = o3; break;
    }
    __shared__ float t[32][33];
    const int tx = threadIdx.x & 31;
    const int ty = threadIdx.x >> 5;          // 0..7
    const int k0 = blockIdx.x * 32;
    const int n0 = blockIdx.y * 32;
#pragma unroll
    for (int i = 0; i < 4; ++i)
        t[ty + i * 8][tx] = w[(long)(k0 + ty + i * 8) * 768 + n0 + tx];
    __syncthreads();
#pragma unroll
    for (int i = 0; i < 4; ++i)
        o[(long)(n0 + ty + i * 8) * 768 + k0 + tx] = f2bf(t[tx][ty + i * 8]);
}

__global__ __launch_bounds__(256) void proj_qkv(
    const unsigned short* __restrict__ xb, const unsigned short* __restrict__ eb,
    const unsigned short* __restrict__ wqt, const unsigned short* __restrict__ wkt,
    const unsigned short* __restrict__ wvt,
    const float* __restrict__ bq, const float* __restrict__ bk,
    const float* __restrict__ bv,
    unsigned short* __restrict__ q, unsigned short* __restrict__ k,
    unsigned short* __restrict__ vt)
{
    const unsigned short *A, *Bt; const float* bias; unsigned short* C;
    int trans = 0;
    switch (blockIdx.z) {
        case 0:  A = xb; Bt = wqt; bias = bq; C = q;  break;
        case 1:  A = eb; Bt = wkt; bias = bk; C = k;  break;
        default: A = eb; Bt = wvt; bias = bv; C = vt; trans = 1; break;
    }
    gemm_core<128>(A, Bt, 768, nullptr, C, 768, trans, bias, 1.0f);
}

__global__ __launch_bounds__(256) void gemm_bt64(
    const unsigned short* __restrict__ A, long sA,
    const unsigned short* __restrict__ Bt, long sB,
    float* __restrict__ Cf, unsigned short* __restrict__ Cb, long sC,
    int K, int ldc, const float* __restrict__ bias, float scale)
{
    const long z = blockIdx.z;
    gemm_core<64>(A + z * sA, Bt + z * sB, K,
                  Cf ? Cf + z * sC : nullptr,
                  Cb ? Cb + z * sC : nullptr,
                  ldc, 0, bias, scale);
}

__global__ __launch_bounds__(256) void softmax_rows(
    const float* __restrict__ S, unsigned short* __restrict__ P)
{
    const long row = blockIdx.x;                 // 8192 rows of 1024
    const float* s = S + row * 1024;
    unsigned short* p = P + row * 1024;
    const int tid  = threadIdx.x;
    const int lane = tid & 63;
    const int wave = tid >> 6;

    float4 v = ((const float4*)s)[tid];
    float m = fmaxf(fmaxf(v.x, v.y), fmaxf(v.z, v.w));
#pragma unroll
    for (int off = 32; off > 0; off >>= 1)
        m = fmaxf(m, __shfl_xor(m, off));
    __shared__ float redm[4], reds[4];
    if (lane == 0) redm[wave] = m;
    __syncthreads();
    m = fmaxf(fmaxf(redm[0], redm[1]), fmaxf(redm[2], redm[3]));

    const float e0 = __expf(v.x - m), e1 = __expf(v.y - m);
    const float e2 = __expf(v.z - m), e3 = __expf(v.w - m);
    float sum = e0 + e1 + e2 + e3;
#pragma unroll
    for (int off = 32; off > 0; off >>= 1)
        sum += __shfl_xor(sum, off);
    if (lane == 0) reds[wave] = sum;
    __syncthreads();
    const float inv = 1.0f / (reds[0] + reds[1] + reds[2] + reds[3]);

    ushort4 o;
    o.x = f2bf(e0 * inv); o.y = f2bf(e1 * inv);
    o.z = f2bf(e2 * inv); o.w = f2bf(e3 * inv);
    ((ushort4*)p)[tid] = o;
}

// ---------------------------------------------------------------------------

extern "C" void kernel_launch(void* const* d_in, const int* in_sizes, int n_in,
                              void* d_out, int out_size, void* d_ws, size_t ws_size,
                              hipStream_t stream) {
    const float* x   = (const float*)d_in[0];
    const float* enc = (const float*)d_in[1];
    const float* Wq  = (const float*)d_in[2];
    const float* bq  = (const float*)d_in[3];
    const float* Wk  = (const float*)d_in[4];
    const float* bk  = (const float*)d_in[5];
    const float* Wv  = (const float*)d_in[6];
    const float* bv  = (const float*)d_in[7];
    const float* Wp  = (const float*)d_in[8];
    const float* bp  = (const float*)d_in[9];
    float* out = (float*)d_out;

    // workspace layout (bytes); peak need ~101.2 MB
    char* ws = (char*)d_ws;
    unsigned short* xb  = (unsigned short*)(ws + 0);         // 12582912
    unsigned short* eb  = (unsigned short*)(ws + 12582912);  // 12582912
    unsigned short* q   = (unsigned short*)(ws + 25165824);  // 12582912
    unsigned short* k   = (unsigned short*)(ws + 37748736);  // 12582912
    unsigned short* vt  = (unsigned short*)(ws + 50331648);  // 12582912 [B][H][S]
    unsigned short* wqt = (unsigned short*)(ws + 62914560);  // 1179648
    unsigned short* wkt = (unsigned short*)(ws + 64094208);  // 1179648
    unsigned short* wvt = (unsigned short*)(ws + 65273856);  // 1179648
    unsigned short* wpt = (unsigned short*)(ws + 66453504);  // 1179648
    float*          sc  = (float*)(ws + 67633152);           // 33554432 fp32 scores
    unsigned short* p   = (unsigned short*)(ws + 0);         // 16777216, overlays xb/eb (dead)
    unsigned short* ao  = (unsigned short*)(ws + 67633152);  // 12582912, overlays sc (dead)

    const float scale = 0.03608439182435161f;  // 1/sqrt(768)

    // 1. fp32 -> bf16 for x and encoder_out (6291456 floats each, float4-wide)
    convert_inputs<<<12288, 256, 0, stream>>>(x, enc, xb, eb, 1572864);

    // 2. W^T bf16 for all four weights
    transpose_w<<<dim3(24, 24, 4), 256, 0, stream>>>(Wq, Wk, Wv, Wp, wqt, wkt, wvt, wpt);

    // 3. q/k/v projections (z: 0=q, 1=k, 2=v-transposed), 128x128 tiles
    proj_qkv<<<dim3(64, 6, 3), 256, 0, stream>>>(xb, eb, wqt, wkt, wvt, bq, bk, bv, q, k, vt);

    // 4. scores = q k^T * scale (fp32), batched over z=8, 128x64 tiles
    gemm_bt64<<<dim3(8, 16, 8), 256, 0, stream>>>(
        q, 786432L, k, 786432L, sc, (unsigned short*)nullptr, 1048576L,
        768, 1024, (const float*)nullptr, scale);

    // 5. softmax rows -> bf16 P
    softmax_rows<<<8192, 256, 0, stream>>>(sc, p);

    // 6. ao = P @ V  (Bt = v_t [H][S]), batched, 128x64 tiles
    gemm_bt64<<<dim3(8, 12, 8), 256, 0, stream>>>(
        p, 1048576L, vt, 786432L, (float*)nullptr, ao, 786432L,
        1024, 768, (const float*)nullptr, 1.0f);

    // 7. out = ao @ Wp + bp (fp32), 128x64 tiles
    gemm_bt64<<<dim3(64, 12, 1), 256, 0, stream>>>(
        ao, 0L, wpt, 0L, out, (unsigned short*)nullptr, 0L,
        768, 768, bp, 1.0f);
}